// Round 1
// baseline (110.162 us; speedup 1.0000x reference)
//
#include <hip/hip_runtime.h>
#include <hip/hip_bf16.h>
#include <stdint.h>

// bf16 MFMA operand: 8 bf16 in 4 VGPRs (guide: short8 typedef, compile-verified on gfx950)
typedef short bf16x8 __attribute__((ext_vector_type(8)));
typedef float f32x16 __attribute__((ext_vector_type(16)));

#define NROWS 8192
#define CDIM  128
#define TEMP  0.07f
// log2(e)/0.07
#define C1F   20.6099291555566248f

__device__ __forceinline__ float bf2f(unsigned short u) {
  union { unsigned int i; float f; } x; x.i = ((unsigned int)u) << 16; return x.f;
}
__device__ __forceinline__ unsigned short f2bf(float f) {
  union { float f; unsigned int i; } x; x.f = f;
  unsigned int r = x.i + 0x7fffu + ((x.i >> 16) & 1u);  // RNE
  return (unsigned short)(r >> 16);
}
__device__ __forceinline__ float fexp2(float x) {
#if __has_builtin(__builtin_amdgcn_exp2f)
  return __builtin_amdgcn_exp2f(x);
#else
  return exp2f(x);
#endif
}

// ---------------------------------------------------------------------------
// K1: pack features (8 g-slices of [128 c][1024 hw] fp32) -> X bf16 [8192][128]
// row n = g*1024 + hw  (valid ordering: loss is row-permutation invariant)
// LDS transpose so both global read and write are coalesced.
// ---------------------------------------------------------------------------
__global__ __launch_bounds__(256) void k_pack(const float* __restrict__ F,
                                              unsigned short* __restrict__ Xb) {
  __shared__ float lds[128 * 33];
  const int g   = blockIdx.x >> 5;          // 0..7
  const int hw0 = (blockIdx.x & 31) << 5;   // 0,32,..,992
  const int tid = threadIdx.x;
#pragma unroll
  for (int p = 0; p < 16; ++p) {
    int c  = p * 8 + (tid >> 5);
    int hw = hw0 + (tid & 31);
    lds[c * 33 + (tid & 31)] = F[(g * 128 + c) * 1024 + hw];
  }
  __syncthreads();
#pragma unroll
  for (int p = 0; p < 16; ++p) {
    int hwl = p * 2 + (tid >> 7);
    int c   = tid & 127;
    int row = g * 1024 + hw0 + hwl;
    Xb[row * 128 + c] = f2bf(lds[c * 33 + hwl]);
  }
}

// ---------------------------------------------------------------------------
// K2: label-group sums G[4][128] (fp32, from bf16 X for consistency with MFMA)
// + histogram of labels (block 0). Grid: 16 row-chunks x 8 c-chunks = 128.
// ---------------------------------------------------------------------------
__global__ __launch_bounds__(256) void k_gsum(const unsigned short* __restrict__ Xb,
                                              const int* __restrict__ labels,
                                              float* __restrict__ G,
                                              int* __restrict__ hist) {
  const int tid    = threadIdx.x;
  const int lane   = tid & 63;
  const int rchunk = blockIdx.x >> 3;   // 0..15
  const int cbase  = (blockIdx.x & 7) * 16;
  const int cl     = tid & 15;          // c within chunk
  const int rg     = tid >> 4;          // 0..15 row phase
  float a0 = 0.f, a1 = 0.f, a2 = 0.f, a3 = 0.f;
  const int nend = rchunk * 512 + 512;
  for (int n = rchunk * 512 + rg; n < nend; n += 16) {
    int   lab = labels[n];
    float v   = bf2f(Xb[n * 128 + cbase + cl]);
    a0 += (lab == 0) ? v : 0.f;
    a1 += (lab == 1) ? v : 0.f;
    a2 += (lab == 2) ? v : 0.f;
    a3 += (lab == 3) ? v : 0.f;
  }
  // sum the 4 row-phases within the wave that share a c
  a0 += __shfl_xor(a0, 16, 64); a0 += __shfl_xor(a0, 32, 64);
  a1 += __shfl_xor(a1, 16, 64); a1 += __shfl_xor(a1, 32, 64);
  a2 += __shfl_xor(a2, 16, 64); a2 += __shfl_xor(a2, 32, 64);
  a3 += __shfl_xor(a3, 16, 64); a3 += __shfl_xor(a3, 32, 64);
  if (lane < 16) {
    int c = cbase + lane;
    atomicAdd(&G[0 * 128 + c], a0);
    atomicAdd(&G[1 * 128 + c], a1);
    atomicAdd(&G[2 * 128 + c], a2);
    atomicAdd(&G[3 * 128 + c], a3);
  }
  if (blockIdx.x == 0) {
    int h0 = 0, h1 = 0, h2 = 0, h3 = 0;
    for (int n = tid; n < NROWS; n += 256) {
      int lab = labels[n];
      h0 += (lab == 0); h1 += (lab == 1); h2 += (lab == 2); h3 += (lab == 3);
    }
    for (int m = 1; m < 64; m <<= 1) {
      h0 += __shfl_xor(h0, m, 64); h1 += __shfl_xor(h1, m, 64);
      h2 += __shfl_xor(h2, m, 64); h3 += __shfl_xor(h3, m, 64);
    }
    if (lane == 0) {
      atomicAdd(&hist[0], h0); atomicAdd(&hist[1], h1);
      atomicAdd(&hist[2], h2); atomicAdd(&hist[3], h3);
    }
  }
}

// ---------------------------------------------------------------------------
// K3: streaming X @ X^T with fused exp-sum.
// Grid: 64 rowBlocks x 16 colSplits = 1024 blocks, 256 thr (4 waves).
// Wave w owns rows rowBlock*128 + w*32 .. +31; A frags live in 16 VGPRs.
// B tiles (32 cols x 128 k) double-buffered in LDS, chunk-transposed+padded:
// 16B unit (kchunk c, col n) at index c*33+n  -> conflict-free ds_read_b128.
// S[row] += sum_j exp2(d_ij * log2e/T), diagonal excluded in-loop.
// ---------------------------------------------------------------------------
__global__ __launch_bounds__(256, 4) void k_main(const unsigned short* __restrict__ Xb,
                                                 float* __restrict__ S) {
  __shared__ int4 ldsB[2][16 * 33];
  const int tid      = threadIdx.x;
  const int lane     = tid & 63;
  const int wave     = tid >> 6;
  const int rowBlock = blockIdx.x >> 4;
  const int split    = blockIdx.x & 15;
  const int r0       = rowBlock * 128 + wave * 32;
  const int col0     = split * 512;
  const int m        = lane & 31;
  const int half     = lane >> 5;

  // A fragments for the wave's 32 rows, full K=128 (scattered 16B, one-time, L2)
  bf16x8 afrag[8];
#pragma unroll
  for (int s = 0; s < 8; ++s)
    afrag[s] = *(const bf16x8*)(Xb + (r0 + m) * CDIM + (half + 2 * s) * 8);

  float accS[16];
#pragma unroll
  for (int r = 0; r < 16; ++r) accS[r] = 0.f;

  // staging: thread -> col n_l (0..31), chunk-pair bq (0..7); coalesced 2KB/wave
  const int n_l = tid >> 3;
  const int bq  = tid & 7;
  const unsigned short* src = Xb + (col0 + n_l) * CDIM + bq * 16;
  int4 v0 = *(const int4*)src;
  int4 v1 = *(const int4*)(src + 8);
  ldsB[0][(2 * bq) * 33 + n_l]     = v0;
  ldsB[0][(2 * bq + 1) * 33 + n_l] = v1;
  src += 32 * CDIM;
  v0 = *(const int4*)src;
  v1 = *(const int4*)(src + 8);

  for (int t = 0; t < 16; ++t) {
    __syncthreads();
    if (t < 15) {
      ldsB[(t + 1) & 1][(2 * bq) * 33 + n_l]     = v0;
      ldsB[(t + 1) & 1][(2 * bq + 1) * 33 + n_l] = v1;
    }
    if (t < 14) {
      src += 32 * CDIM;
      v0 = *(const int4*)src;
      v1 = *(const int4*)(src + 8);
    }
    const int cur = t & 1;
    f32x16 acc;
#pragma unroll
    for (int r = 0; r < 16; ++r) acc[r] = 0.f;
#pragma unroll
    for (int s = 0; s < 8; ++s) {
      bf16x8 bfrag = *(const bf16x8*)&ldsB[cur][(half + 2 * s) * 33 + m];
      acc = __builtin_amdgcn_mfma_f32_32x32x16_bf16(afrag[s], bfrag, acc, 0, 0, 0);
    }
    const int colbase = col0 + t * 32;
    if (r0 == colbase) {  // only tile that can contain the diagonal
      const int colg = colbase + m;
#pragma unroll
      for (int r = 0; r < 16; ++r) {
        int   row = r0 + (r & 3) + 8 * (r >> 2) + 4 * half;
        float arg = (row == colg) ? -1e30f : acc[r] * C1F;
        accS[r] += fexp2(arg);
      }
    } else {
#pragma unroll
      for (int r = 0; r < 16; ++r) accS[r] += fexp2(acc[r] * C1F);
    }
  }

  // reduce over the 32 columns (lanes) of each half, then one atomic per row
#pragma unroll
  for (int r = 0; r < 16; ++r) {
    float v = accS[r];
    v += __shfl_xor(v, 1, 64);
    v += __shfl_xor(v, 2, 64);
    v += __shfl_xor(v, 4, 64);
    v += __shfl_xor(v, 8, 64);
    v += __shfl_xor(v, 16, 64);
    accS[r] = v;
  }
  if (m == 0) {
#pragma unroll
    for (int r = 0; r < 16; ++r) {
      int row = r0 + (r & 3) + 8 * (r >> 2) + 4 * half;
      atomicAdd(&S[row], accS[r]);
    }
  }
}

// ---------------------------------------------------------------------------
// K4: per-row loss + reduction.
// loss_i = log(S_i) - (dot(x_i,G_lab) - |x_i|^2) / (T * (hist[lab]-1))
// ---------------------------------------------------------------------------
__global__ __launch_bounds__(256) void k_loss(const unsigned short* __restrict__ Xb,
                                              const int* __restrict__ labels,
                                              const float* __restrict__ S,
                                              const float* __restrict__ G,
                                              const int* __restrict__ hist,
                                              float* __restrict__ sumLoss) {
  const int i   = blockIdx.x * 256 + threadIdx.x;
  const int lab = labels[i];
  const float* g = G + lab * 128;
  const unsigned short* x = Xb + i * CDIM;
  float dot = 0.f, nrm = 0.f;
#pragma unroll
  for (int cc = 0; cc < 16; ++cc) {
    int4 q = *(const int4*)(x + cc * 8);
    const unsigned int* qs = (const unsigned int*)&q;
#pragma unroll
    for (int j = 0; j < 4; ++j) {
      unsigned int u = qs[j];
      float lo = __uint_as_float(u << 16);
      float hi = __uint_as_float(u & 0xffff0000u);
      int   ci = cc * 8 + j * 2;
      dot += lo * g[ci] + hi * g[ci + 1];
      nrm += lo * lo + hi * hi;
    }
  }
  float Si   = S[i];
  float cnt  = (float)(hist[lab] - 1);
  float loss = logf(Si) - (dot - nrm) / (TEMP * cnt);
  float contrib = (lab != 0) ? loss : 0.f;
  for (int mm = 1; mm < 64; mm <<= 1) contrib += __shfl_xor(contrib, mm, 64);
  __shared__ float ws4[4];
  if ((threadIdx.x & 63) == 0) ws4[threadIdx.x >> 6] = contrib;
  __syncthreads();
  if (threadIdx.x == 0) atomicAdd(sumLoss, ws4[0] + ws4[1] + ws4[2] + ws4[3]);
}

__global__ void k_final(const float* __restrict__ sumLoss,
                        const int* __restrict__ hist,
                        float* __restrict__ out) {
  out[0] = sumLoss[0] / (float)(NROWS - hist[0]);
}

// ---------------------------------------------------------------------------
extern "C" void kernel_launch(void* const* d_in, const int* in_sizes, int n_in,
                              void* d_out, int out_size, void* d_ws, size_t ws_size,
                              hipStream_t stream) {
  const float* F      = (const float*)d_in[0];
  const int*   labels = (const int*)d_in[1];
  char* ws = (char*)d_ws;

  // workspace layout
  unsigned short* Xb      = (unsigned short*)ws;                       // 2 MB
  const size_t    offS    = (size_t)NROWS * CDIM * 2;                  // 2097152
  float*          S       = (float*)(ws + offS);                       // 32 KB
  float*          G       = (float*)(ws + offS + 32768);               // 2 KB
  int*            hist    = (int*)(ws + offS + 32768 + 2048);          // 16 B
  float*          sumLoss = (float*)(ws + offS + 32768 + 2048 + 16);   // 4 B

  hipMemsetAsync(ws + offS, 0, 32768 + 2048 + 16 + 4, stream);

  hipLaunchKernelGGL(k_pack, dim3(256), dim3(256), 0, stream, F, Xb);
  hipLaunchKernelGGL(k_gsum, dim3(128), dim3(256), 0, stream, Xb, labels, G, hist);
  hipLaunchKernelGGL(k_main, dim3(1024), dim3(256), 0, stream, Xb, S);
  hipLaunchKernelGGL(k_loss, dim3(32), dim3(256), 0, stream, Xb, labels, S, G, hist, sumLoss);
  hipLaunchKernelGGL(k_final, dim3(1), dim3(1), 0, stream, sumLoss, hist, (float*)d_out);
}

// Round 2
// 99.758 us; speedup vs baseline: 1.1043x; 1.1043x over previous
//
#include <hip/hip_runtime.h>
#include <hip/hip_bf16.h>
#include <stdint.h>

// bf16 MFMA operand: 8 bf16 in 4 VGPRs
typedef short bf16x8 __attribute__((ext_vector_type(8)));
typedef float f32x16 __attribute__((ext_vector_type(16)));

#define NROWS 8192
#define CDIM  128
#define TEMP  0.07f
// log2(e)/0.07
#define C1F   20.6099291555566248f

// ws layout offsets (bytes) past Xb (2 MB)
#define OFF_S    0
#define OFF_G    32768
#define OFF_HIST (32768 + 2048)
#define OFF_SUM  (32768 + 2048 + 16)
#define OFF_TKT  (32768 + 2048 + 16 + 4)
#define ZBYTES   (32768 + 2048 + 16 + 4 + 4)
#define ZWORDS   (ZBYTES / 4)   // 8710

__device__ __forceinline__ float bf2f(unsigned short u) {
  union { unsigned int i; float f; } x; x.i = ((unsigned int)u) << 16; return x.f;
}
__device__ __forceinline__ unsigned short f2bf(float f) {
  union { float f; unsigned int i; } x; x.f = f;
  unsigned int r = x.i + 0x7fffu + ((x.i >> 16) & 1u);  // RNE
  return (unsigned short)(r >> 16);
}
__device__ __forceinline__ float fexp2(float x) {
#if __has_builtin(__builtin_amdgcn_exp2f)
  return __builtin_amdgcn_exp2f(x);
#else
  return exp2f(x);
#endif
}

// ---------------------------------------------------------------------------
// K1: pack features -> X bf16 [8192][128]  (+ zero the stats region, replacing
// the hipMemsetAsync node). row n = g*1024 + hw (loss is row-perm invariant).
// ---------------------------------------------------------------------------
__global__ __launch_bounds__(256) void k_pack(const float* __restrict__ F,
                                              unsigned short* __restrict__ Xb,
                                              float* __restrict__ zbase) {
  const int tid = threadIdx.x;
  // fold-in: zero S/G/hist/sumLoss/ticket (34840 B) across first 35 blocks
  {
    int idx = blockIdx.x * 256 + tid;
    if (idx < ZWORDS) zbase[idx] = 0.0f;
  }
  __shared__ float lds[128 * 33];
  const int g   = blockIdx.x >> 5;          // 0..7
  const int hw0 = (blockIdx.x & 31) << 5;   // 0,32,..,992
#pragma unroll
  for (int p = 0; p < 16; ++p) {
    int c  = p * 8 + (tid >> 5);
    int hw = hw0 + (tid & 31);
    lds[c * 33 + (tid & 31)] = F[(g * 128 + c) * 1024 + hw];
  }
  __syncthreads();
#pragma unroll
  for (int p = 0; p < 16; ++p) {
    int hwl = p * 2 + (tid >> 7);
    int c   = tid & 127;
    int row = g * 1024 + hw0 + hwl;
    Xb[row * 128 + c] = f2bf(lds[c * 33 + hwl]);
  }
}

// ---------------------------------------------------------------------------
// K2 (fused): blocks 0..127  -> label-group sums G[4][128] + histogram
//             blocks 128..1151 -> streaming X @ X^T with fused exp-sum
// Main path: 64 rowBlocks x 16 colSplits. Wave owns 32 rows (A frags resident
// in 32 VGPRs). B tiles: 64 cols / barrier-iteration (2 groups of 32 computed
// sequentially off one buffer), double-buffered, 2-deep register prefetch.
// LDS layout chunk-transposed + pad: int4 (kchunk c, col n) at c*33+n.
// ---------------------------------------------------------------------------
__global__ __launch_bounds__(256, 4) void k_main(const unsigned short* __restrict__ Xb,
                                                 const int* __restrict__ labels,
                                                 float* __restrict__ S,
                                                 float* __restrict__ G,
                                                 int* __restrict__ hist) {
  __shared__ int4 ldsB[2][2][16 * 33];
  const int bid = blockIdx.x;
  const int tid = threadIdx.x;
  const int lane = tid & 63;

  if (bid < 128) {
    // ---- gsum + hist path ----
    const int rchunk = bid >> 3;          // 0..15
    const int cbase  = (bid & 7) * 16;
    const int cl     = tid & 15;
    const int rg     = tid >> 4;
    float a0 = 0.f, a1 = 0.f, a2 = 0.f, a3 = 0.f;
    const int nend = rchunk * 512 + 512;
    for (int n = rchunk * 512 + rg; n < nend; n += 16) {
      int   lab = labels[n];
      float v   = bf2f(Xb[n * 128 + cbase + cl]);
      a0 += (lab == 0) ? v : 0.f;
      a1 += (lab == 1) ? v : 0.f;
      a2 += (lab == 2) ? v : 0.f;
      a3 += (lab == 3) ? v : 0.f;
    }
    a0 += __shfl_xor(a0, 16, 64); a0 += __shfl_xor(a0, 32, 64);
    a1 += __shfl_xor(a1, 16, 64); a1 += __shfl_xor(a1, 32, 64);
    a2 += __shfl_xor(a2, 16, 64); a2 += __shfl_xor(a2, 32, 64);
    a3 += __shfl_xor(a3, 16, 64); a3 += __shfl_xor(a3, 32, 64);
    if (lane < 16) {
      int c = cbase + lane;
      atomicAdd(&G[0 * 128 + c], a0);
      atomicAdd(&G[1 * 128 + c], a1);
      atomicAdd(&G[2 * 128 + c], a2);
      atomicAdd(&G[3 * 128 + c], a3);
    }
    if (bid == 0) {
      int h0 = 0, h1 = 0, h2 = 0, h3 = 0;
      for (int n = tid; n < NROWS; n += 256) {
        int lab = labels[n];
        h0 += (lab == 0); h1 += (lab == 1); h2 += (lab == 2); h3 += (lab == 3);
      }
      for (int mm = 1; mm < 64; mm <<= 1) {
        h0 += __shfl_xor(h0, mm, 64); h1 += __shfl_xor(h1, mm, 64);
        h2 += __shfl_xor(h2, mm, 64); h3 += __shfl_xor(h3, mm, 64);
      }
      if (lane == 0) {
        atomicAdd(&hist[0], h0); atomicAdd(&hist[1], h1);
        atomicAdd(&hist[2], h2); atomicAdd(&hist[3], h3);
      }
    }
    return;
  }

  // ---- main MFMA path ----
  const int b        = bid - 128;
  const int wave     = tid >> 6;
  const int rowBlock = b >> 4;
  const int split    = b & 15;
  const int r0       = rowBlock * 128 + wave * 32;
  const int col0     = split * 512;
  const int m        = lane & 31;
  const int half     = lane >> 5;

  bf16x8 afrag[8];
#pragma unroll
  for (int s = 0; s < 8; ++s)
    afrag[s] = *(const bf16x8*)(Xb + (r0 + m) * CDIM + (half + 2 * s) * 8);

  float accS[16];
#pragma unroll
  for (int r = 0; r < 16; ++r) accS[r] = 0.f;

  // staging: col n_l (0..31) in group, chunk-pair bq (0..7); 64 cols/iteration
  const int n_l = tid >> 3;
  const int bq  = tid & 7;
  const unsigned short* src = Xb + (col0 + n_l) * CDIM + bq * 16;
  int4 v0 = *(const int4*)src;
  int4 v1 = *(const int4*)(src + 8);
  int4 v2 = *(const int4*)(src + 32 * CDIM);
  int4 v3 = *(const int4*)(src + 32 * CDIM + 8);
  ldsB[0][0][(2 * bq) * 33 + n_l]     = v0;
  ldsB[0][0][(2 * bq + 1) * 33 + n_l] = v1;
  ldsB[0][1][(2 * bq) * 33 + n_l]     = v2;
  ldsB[0][1][(2 * bq + 1) * 33 + n_l] = v3;
  src += 64 * CDIM;
  v0 = *(const int4*)src;
  v1 = *(const int4*)(src + 8);
  v2 = *(const int4*)(src + 32 * CDIM);
  v3 = *(const int4*)(src + 32 * CDIM + 8);

  for (int t = 0; t < 8; ++t) {
    __syncthreads();
    if (t < 7) {
      const int nb = (t + 1) & 1;
      ldsB[nb][0][(2 * bq) * 33 + n_l]     = v0;
      ldsB[nb][0][(2 * bq + 1) * 33 + n_l] = v1;
      ldsB[nb][1][(2 * bq) * 33 + n_l]     = v2;
      ldsB[nb][1][(2 * bq + 1) * 33 + n_l] = v3;
    }
    if (t < 6) {
      src += 64 * CDIM;
      v0 = *(const int4*)src;
      v1 = *(const int4*)(src + 8);
      v2 = *(const int4*)(src + 32 * CDIM);
      v3 = *(const int4*)(src + 32 * CDIM + 8);
    }
    const int cur = t & 1;
#pragma unroll
    for (int u = 0; u < 2; ++u) {
      f32x16 acc;
#pragma unroll
      for (int r = 0; r < 16; ++r) acc[r] = 0.f;
#pragma unroll
      for (int s = 0; s < 8; ++s) {
        bf16x8 bfrag = *(const bf16x8*)&ldsB[cur][u][(half + 2 * s) * 33 + m];
        acc = __builtin_amdgcn_mfma_f32_32x32x16_bf16(afrag[s], bfrag, acc, 0, 0, 0);
      }
      const int colbase = col0 + t * 64 + u * 32;
      if (r0 == colbase) {  // the only tile that can contain the diagonal
        const int colg = colbase + m;
#pragma unroll
        for (int r = 0; r < 16; ++r) {
          int   row = r0 + (r & 3) + 8 * (r >> 2) + 4 * half;
          float arg = (row == colg) ? -1e30f : acc[r] * C1F;
          accS[r] += fexp2(arg);
        }
      } else {
#pragma unroll
        for (int r = 0; r < 16; ++r) accS[r] += fexp2(acc[r] * C1F);
      }
    }
  }

  // reduce over the 32 columns (lanes) of each half, one atomic per row
#pragma unroll
  for (int r = 0; r < 16; ++r) {
    float v = accS[r];
    v += __shfl_xor(v, 1, 64);
    v += __shfl_xor(v, 2, 64);
    v += __shfl_xor(v, 4, 64);
    v += __shfl_xor(v, 8, 64);
    v += __shfl_xor(v, 16, 64);
    accS[r] = v;
  }
  if (m == 0) {
#pragma unroll
    for (int r = 0; r < 16; ++r) {
      int row = r0 + (r & 3) + 8 * (r >> 2) + 4 * half;
      atomicAdd(&S[row], accS[r]);
    }
  }
}

// ---------------------------------------------------------------------------
// K3: per-row loss + global reduction + completion-ticket final division.
// loss_i = log(S_i) - (dot(x_i,G_lab) - |x_i|^2) / (T * (hist[lab]-1))
// ---------------------------------------------------------------------------
__global__ __launch_bounds__(256) void k_loss(const unsigned short* __restrict__ Xb,
                                              const int* __restrict__ labels,
                                              const float* __restrict__ S,
                                              const float* __restrict__ G,
                                              const int* __restrict__ hist,
                                              float* __restrict__ sumLoss,
                                              int* __restrict__ ticket,
                                              float* __restrict__ out) {
  const int i   = blockIdx.x * 256 + threadIdx.x;
  const int lab = labels[i];
  const float* g = G + lab * 128;
  const unsigned short* x = Xb + i * CDIM;
  float dot = 0.f, nrm = 0.f;
#pragma unroll
  for (int cc = 0; cc < 16; ++cc) {
    int4 q = *(const int4*)(x + cc * 8);
    const unsigned int* qs = (const unsigned int*)&q;
#pragma unroll
    for (int j = 0; j < 4; ++j) {
      unsigned int u = qs[j];
      float lo = __uint_as_float(u << 16);
      float hi = __uint_as_float(u & 0xffff0000u);
      int   ci = cc * 8 + j * 2;
      dot += lo * g[ci] + hi * g[ci + 1];
      nrm += lo * lo + hi * hi;
    }
  }
  float Si   = S[i];
  float cnt  = (float)(hist[lab] - 1);
  float loss = logf(Si) - (dot - nrm) / (TEMP * cnt);
  float contrib = (lab != 0) ? loss : 0.f;
  for (int mm = 1; mm < 64; mm <<= 1) contrib += __shfl_xor(contrib, mm, 64);
  __shared__ float ws4[4];
  if ((threadIdx.x & 63) == 0) ws4[threadIdx.x >> 6] = contrib;
  __syncthreads();
  if (threadIdx.x == 0) {
    atomicAdd(sumLoss, ws4[0] + ws4[1] + ws4[2] + ws4[3]);
    __threadfence();
    int t = atomicAdd(ticket, 1);
    if (t == 31) {  // last block: all 32 sumLoss adds are ordered before this
      float total = atomicAdd(sumLoss, 0.0f);  // atomic read sees all adds
      out[0] = total / (float)(NROWS - hist[0]);
    }
  }
}

// ---------------------------------------------------------------------------
extern "C" void kernel_launch(void* const* d_in, const int* in_sizes, int n_in,
                              void* d_out, int out_size, void* d_ws, size_t ws_size,
                              hipStream_t stream) {
  const float* F      = (const float*)d_in[0];
  const int*   labels = (const int*)d_in[1];
  char* ws = (char*)d_ws;

  unsigned short* Xb      = (unsigned short*)ws;                 // 2 MB
  const size_t    offS    = (size_t)NROWS * CDIM * 2;            // 2097152
  float*          S       = (float*)(ws + offS + OFF_S);
  float*          G       = (float*)(ws + offS + OFF_G);
  int*            hist    = (int*)(ws + offS + OFF_HIST);
  float*          sumLoss = (float*)(ws + offS + OFF_SUM);
  int*            ticket  = (int*)(ws + offS + OFF_TKT);

  hipLaunchKernelGGL(k_pack, dim3(256), dim3(256), 0, stream, F, Xb, S);
  hipLaunchKernelGGL(k_main, dim3(1152), dim3(256), 0, stream, Xb, labels, S, G, hist);
  hipLaunchKernelGGL(k_loss, dim3(32), dim3(256), 0, stream, Xb, labels, S, G, hist,
                     sumLoss, ticket, (float*)d_out);
}